// Round 6
// baseline (186.691 us; speedup 1.0000x reference)
//
#include <hip/hip_runtime.h>
#include <hip/hip_bf16.h>
#include <math.h>

typedef unsigned short u16;
typedef __attribute__((ext_vector_type(8))) __bf16 bf16x8;
typedef __attribute__((ext_vector_type(4))) float f32x4;
typedef __attribute__((ext_vector_type(16))) float f32x16;
typedef __attribute__((ext_vector_type(8))) unsigned short u16x8;
typedef __attribute__((ext_vector_type(4))) unsigned int u32x4;
typedef __attribute__((ext_vector_type(2))) unsigned int u32x2;

// ---------- helpers ----------
__device__ __forceinline__ u16 f2bf(float f) {
  union { float f; unsigned u; } x; x.f = f;
  unsigned r = x.u + 0x7fffu + ((x.u >> 16) & 1u);   // RNE
  return (u16)(r >> 16);
}

__device__ __forceinline__ void gload16(const u16* g, u16* l) {
  __builtin_amdgcn_global_load_lds(
      (const __attribute__((address_space(1))) void*)g,
      (__attribute__((address_space(3))) void*)l, 16, 0, 0);
}

#define MFMA16(a, b, c) __builtin_amdgcn_mfma_f32_16x16x32_bf16((a), (b), (c), 0, 0, 0)
#define MFMA32(a, b, c) __builtin_amdgcn_mfma_f32_32x32x16_bf16((a), (b), (c), 0, 0, 0)

// Q pre-scale: 1/sqrt(64) * log2(e)  (softmax done in exp2 domain)
#define QSCALE 0.18033688011112043f

// ---------- cast fp32 -> bf16 (vectorized) ----------
__global__ __launch_bounds__(256) void cast_bf16_kernel(
    const float* __restrict__ in, u16* __restrict__ out, int n4) {
  int i = blockIdx.x * 256 + threadIdx.x;
  if (i >= n4) return;
  f32x4 v = *(const f32x4*)(in + (size_t)i * 4);
  u16 o0 = f2bf(v[0]), o1 = f2bf(v[1]), o2 = f2bf(v[2]), o3 = f2bf(v[3]);
  unsigned lo = (unsigned)o0 | ((unsigned)o1 << 16);
  unsigned hi = (unsigned)o2 | ((unsigned)o3 << 16);
  ((unsigned*)out)[(size_t)i * 2] = lo;
  ((unsigned*)out)[(size_t)i * 2 + 1] = hi;
}

// ---------- shared 128x128 / BK=64 bf16 GEMM main loop (C = A * B^T) ----------
__device__ __forceinline__ void gemm_bt_128(
    const u16* __restrict__ A, const u16* __restrict__ B, int K, int m0, int n0,
    u16* As, u16* Bs, f32x4 acc[4][4]) {
  const int tid = threadIdx.x;
  const int lane = tid & 63;
  const int wr = tid >> 7;
  const int wc = (tid >> 6) & 1;
  for (int k0 = 0; k0 < K; k0 += 64) {
    #pragma unroll
    for (int it = 0; it < 4; ++it) {
      int c = it * 256 + tid;
      int row = c >> 3;
      int ko = (c & 7) << 3;
      gload16(A + (size_t)(m0 + row) * K + (k0 + ko), As + c * 8);
      gload16(B + (size_t)(n0 + row) * K + (k0 + ko), Bs + c * 8);
    }
    __syncthreads();
    #pragma unroll
    for (int kk = 0; kk < 2; ++kk) {
      bf16x8 a[4], b[4];
      #pragma unroll
      for (int m = 0; m < 4; ++m)
        a[m] = *(const bf16x8*)(As + ((wr * 64 + m * 16 + (lane & 15)) * 64 +
                                      kk * 32 + ((lane >> 4) << 3)));
      #pragma unroll
      for (int n = 0; n < 4; ++n)
        b[n] = *(const bf16x8*)(Bs + ((wc * 64 + n * 16 + (lane & 15)) * 64 +
                                      kk * 32 + ((lane >> 4) << 3)));
      #pragma unroll
      for (int m = 0; m < 4; ++m)
        #pragma unroll
        for (int n = 0; n < 4; ++n)
          acc[m][n] = MFMA16(a[m], b[n], acc[m][n]);
    }
    __syncthreads();
  }
}

// ---------- GEMM1: qkv = x @ Wqkv^T + b; Q,K per-head [q][d]; V per-head [d][q] ----------
__global__ __launch_bounds__(256) void gemm_qkv_kernel(
    const u16* __restrict__ X, const u16* __restrict__ W, const float* __restrict__ bias,
    u16* __restrict__ Qb, u16* __restrict__ Kb, u16* __restrict__ VTb) {
  __shared__ __align__(16) u16 As[128 * 64];
  __shared__ __align__(16) u16 Bs[128 * 64];
  f32x4 acc[4][4];
  #pragma unroll
  for (int m = 0; m < 4; ++m)
    #pragma unroll
    for (int n = 0; n < 4; ++n) acc[m][n] = (f32x4){0.f, 0.f, 0.f, 0.f};
  const int m0 = blockIdx.y * 128;
  const int n0 = blockIdx.x * 128;
  gemm_bt_128(X, W, 1024, m0, n0, As, Bs, acc);
  const int lane = threadIdx.x & 63;
  const int wr = threadIdx.x >> 7, wc = (threadIdx.x >> 6) & 1;
  #pragma unroll
  for (int m = 0; m < 4; ++m) {
    #pragma unroll
    for (int n = 0; n < 4; ++n) {
      #pragma unroll
      for (int j = 0; j < 4; ++j) {
        int row = m0 + wr * 64 + m * 16 + ((lane >> 4) << 2) + j;
        int col = n0 + wc * 64 + n * 16 + (lane & 15);
        float v = acc[m][n][j] + bias[col];
        int which = col >> 10;
        int rem = col & 1023;
        int h = rem >> 6, d = rem & 63;
        int bb = row >> 11, q = row & 2047;
        int hh = bb * 16 + h;
        if (which == 0) {
          Qb[((size_t)hh * 2048 + q) * 64 + d] = f2bf(v * QSCALE);
        } else if (which == 1) {
          Kb[((size_t)hh * 2048 + q) * 64 + d] = f2bf(v);
        } else {
          VTb[((size_t)hh * 64 + d) * 2048 + q] = f2bf(v);   // transposed
        }
      }
    }
  }
}

// ---------- GEMM2: out = attn @ Wo^T + b (fp32 out) ----------
__global__ __launch_bounds__(256) void gemm_out_kernel(
    const u16* __restrict__ Ain, const u16* __restrict__ W, const float* __restrict__ bias,
    float* __restrict__ out) {
  __shared__ __align__(16) u16 As[128 * 64];
  __shared__ __align__(16) u16 Bs[128 * 64];
  f32x4 acc[4][4];
  #pragma unroll
  for (int m = 0; m < 4; ++m)
    #pragma unroll
    for (int n = 0; n < 4; ++n) acc[m][n] = (f32x4){0.f, 0.f, 0.f, 0.f};
  const int m0 = blockIdx.y * 128;
  const int n0 = blockIdx.x * 128;
  gemm_bt_128(Ain, W, 1024, m0, n0, As, Bs, acc);
  const int lane = threadIdx.x & 63;
  const int wr = threadIdx.x >> 7, wc = (threadIdx.x >> 6) & 1;
  #pragma unroll
  for (int m = 0; m < 4; ++m) {
    #pragma unroll
    for (int n = 0; n < 4; ++n) {
      #pragma unroll
      for (int j = 0; j < 4; ++j) {
        int row = m0 + wr * 64 + m * 16 + ((lane >> 4) << 2) + j;
        int col = n0 + wc * 64 + n * 16 + (lane & 15);
        out[(size_t)row * 1024 + col] = acc[m][n][j] + bias[col];
      }
    }
  }
}

// ---------- causal flash attention: 32-row waves, 32x32x16 MFMA ----------
// Block = 2 waves x 32 q-rows (64-row qblock). KV tile = 64 keys.
// ST = K@Q^T (D[key][q], col=lane&31=q): lane holds 32 P of ONE q-row (16 per
// key-half c; partner lane+32 holds the interleaved keys). Softmax: local + xor32.
// PV as O^T = V^T @ P (col=q): rescale & 1/l are lane-local. P exchange:
// per kstep, 4 shfl_xor(32) + 4 selects build the key-contiguous B-fragment.
// K and V^T both staged via global_load_lds with pre-swizzled sources.
__device__ __forceinline__ void attn_one(
    const u16* __restrict__ Qh, const u16* __restrict__ Kh, const u16* __restrict__ VTh,
    u16* __restrict__ Ob, int bb, int h, int qb,
    u16 (*Ks)[64 * 64], u16 (*Vt)[64 * 64]) {
  const int tid = threadIdx.x, lane = tid & 63, w = tid >> 6;
  const int half = lane >> 5, q31 = lane & 31;
  const int qrow = qb * 64 + w * 32 + q31;

  // Q fragment (B-operand): lane holds Q[qrow][dstep*16 + 8*half + i]
  bf16x8 qf[4];
  #pragma unroll
  for (int ds = 0; ds < 4; ++ds)
    qf[ds] = *(const bf16x8*)(Qh + (size_t)qrow * 64 + ds * 16 + half * 8);

  f32x16 acc_o[2] = {};
  float m_run = -INFINITY, l_run = 0.f;
  const int nt = qb + 1;

  auto stageK = [&](int t, int buf) {
    #pragma unroll
    for (int it = 0; it < 4; ++it) {
      int c = it * 128 + tid;
      int row = c >> 3, b8 = c & 7;
      gload16(Kh + (size_t)(t * 64 + row) * 64 + ((b8 ^ (row & 7)) << 3),
              Ks[buf] + c * 8);
    }
  };
  auto stageV = [&](int t, int buf) {
    #pragma unroll
    for (int it = 0; it < 4; ++it) {
      int c = it * 128 + tid;
      int d = c >> 3, b8 = c & 7;
      int fv = (d + (d >> 3)) & 7;
      gload16(VTh + (size_t)d * 2048 + t * 64 + ((b8 ^ fv) << 3),
              Vt[buf] + c * 8);
    }
  };

  stageK(0, 0);
  stageV(0, 0);
  __syncthreads();

  for (int t = 0; t < nt; ++t) {
    const int cur = t & 1;
    if (t + 1 < nt) { stageK(t + 1, cur ^ 1); stageV(t + 1, cur ^ 1); }

    // ---- ST = K @ Q^T : accs[c] = D[key = c*32 + klocal(r)][q = q31] ----
    f32x16 accs[2] = {};
    __builtin_amdgcn_s_setprio(1);
    #pragma unroll
    for (int c = 0; c < 2; ++c) {
      #pragma unroll
      for (int ds = 0; ds < 4; ++ds) {
        int row = c * 32 + q31;
        int bi = 2 * ds + half;
        bf16x8 kf = *(const bf16x8*)(Ks[cur] + row * 64 + ((bi ^ (row & 7)) << 3));
        accs[c] = MFMA32(kf, qf[ds], accs[c]);
      }
    }
    __builtin_amdgcn_s_setprio(0);

    // causal mask on diagonal tile (klocal(r) = (r&3) + 8*(r>>2) + 4*half)
    if (t == nt - 1) {
      #pragma unroll
      for (int c = 0; c < 2; ++c)
        #pragma unroll
        for (int r = 0; r < 16; ++r) {
          int kg = t * 64 + c * 32 + (r & 3) + 8 * (r >> 2) + 4 * half;
          if (kg > qrow) accs[c][r] = -INFINITY;
        }
    }

    // ---- online softmax (exp2 domain), q-row split across lane/lane+32 ----
    float mj = accs[0][0];
    #pragma unroll
    for (int c = 0; c < 2; ++c)
      #pragma unroll
      for (int r = 0; r < 16; ++r) mj = fmaxf(mj, accs[c][r]);
    mj = fmaxf(mj, __shfl_xor(mj, 32));
    float mn = fmaxf(m_run, mj);
    float sc = exp2f(m_run - mn);
    m_run = mn;
    float rs = 0.f;
    #pragma unroll
    for (int c = 0; c < 2; ++c)
      #pragma unroll
      for (int r = 0; r < 16; ++r) {
        float p = exp2f(accs[c][r] - mn);
        accs[c][r] = p;
        rs += p;
      }
    rs += __shfl_xor(rs, 32);
    l_run = l_run * sc + rs;
    acc_o[0] *= sc;
    acc_o[1] *= sc;

    // ---- pack P: Wp[c][m] = keys {(2m&3)+8*(m>>1)+4*half, +1} (+32c) ----
    unsigned Wp[2][8];
    #pragma unroll
    for (int c = 0; c < 2; ++c)
      #pragma unroll
      for (int m = 0; m < 8; ++m)
        asm("v_cvt_pk_bf16_f32 %0, %1, %2"
            : "=v"(Wp[c][m]) : "v"(accs[c][2 * m]), "v"(accs[c][2 * m + 1]));

    // ---- PV: O^T += V^T @ P, kstep k: B-frag = keys 16k + 8*half + 0..7 ----
    #pragma unroll
    for (int k = 0; k < 4; ++k) {
      const int c = k >> 1, g0 = 4 * (k & 1);
      unsigned x0 = (unsigned)__shfl_xor((int)Wp[c][g0 + 0], 32);
      unsigned x1 = (unsigned)__shfl_xor((int)Wp[c][g0 + 1], 32);
      unsigned x2 = (unsigned)__shfl_xor((int)Wp[c][g0 + 2], 32);
      unsigned x3 = (unsigned)__shfl_xor((int)Wp[c][g0 + 3], 32);
      unsigned pa0 = half ? x2 : Wp[c][g0 + 0];
      unsigned pa1 = half ? x3 : Wp[c][g0 + 1];
      unsigned pa2 = half ? Wp[c][g0 + 2] : x0;
      unsigned pa3 = half ? Wp[c][g0 + 3] : x1;
      bf16x8 pb = __builtin_bit_cast(bf16x8, (u32x4){pa0, pa1, pa2, pa3});
      __builtin_amdgcn_s_setprio(1);
      #pragma unroll
      for (int n = 0; n < 2; ++n) {
        int d = n * 32 + q31;
        int fv = (d + (d >> 3)) & 7;
        int bi = 2 * k + half;
        bf16x8 vf = *(const bf16x8*)(Vt[cur] + d * 64 + ((bi ^ fv) << 3));
        acc_o[n] = MFMA32(vf, pb, acc_o[n]);
      }
      __builtin_amdgcn_s_setprio(0);
    }
    __syncthreads();
  }

  // ---- epilogue: O^T lane-local 1/l; write bf16 rows of [B*C, H] ----
  float invl = 1.0f / l_run;
  #pragma unroll
  for (int n = 0; n < 2; ++n)
    #pragma unroll
    for (int rq = 0; rq < 4; ++rq) {
      int dbase = n * 32 + 8 * rq + 4 * half;
      u16 o0 = f2bf(acc_o[n][4 * rq + 0] * invl);
      u16 o1 = f2bf(acc_o[n][4 * rq + 1] * invl);
      u16 o2 = f2bf(acc_o[n][4 * rq + 2] * invl);
      u16 o3 = f2bf(acc_o[n][4 * rq + 3] * invl);
      unsigned lo = (unsigned)o0 | ((unsigned)o1 << 16);
      unsigned hi = (unsigned)o2 | ((unsigned)o3 << 16);
      size_t idx = ((size_t)(bb * 2048 + qrow)) * 1024 + h * 64 + dbase;
      *(u32x2*)(Ob + idx) = (u32x2){lo, hi};
    }
}

// grid = 32 heads x 16 balanced pairs; block handles qblocks (31-p, p): 33 KV tiles.
__global__ __launch_bounds__(128, 2) void attn_kernel(
    const u16* __restrict__ Qb, const u16* __restrict__ Kb, const u16* __restrict__ VTb,
    u16* __restrict__ Ob) {
  __shared__ __align__(16) u16 Ks[2][64 * 64];
  __shared__ __align__(16) u16 Vt[2][64 * 64];
  const int blk = blockIdx.x;
  const int p = blk & 15;
  const int bh = blk >> 4;             // 0..31 (b*16+h)
  const size_t base = (size_t)bh * 2048 * 64;   // == bh*64*2048 for V^T too
  const int bb = bh >> 4, h = bh & 15;
  attn_one(Qb + base, Kb + base, VTb + base, Ob, bb, h, 31 - p, Ks, Vt);
  attn_one(Qb + base, Kb + base, VTb + base, Ob, bb, h, p, Ks, Vt);
}

// ---------- launch ----------
extern "C" void kernel_launch(void* const* d_in, const int* in_sizes, int n_in,
                              void* d_out, int out_size, void* d_ws, size_t ws_size,
                              hipStream_t stream) {
  const float* x    = (const float*)d_in[0];   // [2,2048,1024]
  const float* wqkv = (const float*)d_in[1];   // [3072,1024]
  const float* bqkv = (const float*)d_in[2];   // [3072]
  const float* wo   = (const float*)d_in[3];   // [1024,1024]
  const float* bo   = (const float*)d_in[4];   // [1024]
  float* out = (float*)d_out;                  // [4096,1024] fp32

  const size_t MB = 1u << 20;
  char* ws = (char*)d_ws;
  u16* x_bf  = (u16*)(ws);             // 8 MB
  u16* wq_bf = (u16*)(ws + 8 * MB);    // 6 MB
  u16* wo_bf = (u16*)(ws + 14 * MB);   // 2 MB
  u16* q_buf = (u16*)(ws + 16 * MB);   // 8 MB  [B,nh,C,64]
  u16* k_buf = (u16*)(ws + 24 * MB);   // 8 MB  [B,nh,C,64]
  u16* vt_buf= (u16*)(ws + 32 * MB);   // 8 MB  [B,nh,64,C]  (transposed)
  u16* a_out = (u16*)(ws + 40 * MB);   // 8 MB  [4096,1024]

  cast_bf16_kernel<<<4096, 256, 0, stream>>>(x, x_bf, 1048576);
  cast_bf16_kernel<<<3072, 256, 0, stream>>>(wqkv, wq_bf, 786432);
  cast_bf16_kernel<<<1024, 256, 0, stream>>>(wo, wo_bf, 262144);

  gemm_qkv_kernel<<<dim3(24, 32), 256, 0, stream>>>(x_bf, wq_bf, bqkv,
                                                    q_buf, k_buf, vt_buf);
  attn_kernel<<<512, 128, 0, stream>>>(q_buf, k_buf, vt_buf, a_out);
  gemm_out_kernel<<<dim3(8, 32), 256, 0, stream>>>(a_out, wo_bf, bo, out);
}